// Round 5
// baseline (173.068 us; speedup 1.0000x reference)
//
#include <hip/hip_runtime.h>
#include <hip/hip_fp16.h>
#include <math.h>

#define HID 64
#define CBITS 6
#define CSZ 64           // nodes per bucket
#define MAXB 2048        // max buckets supported (N <= 131072)
#define CAP 832          // record slots per bucket (mean 640, sigma ~25 -> +7.6 sigma)
#define PB 896           // proj blocks in the fused mid kernel
#define MSB 256          // multisplit blocks in the fused mid kernel
#define XSTR 17          // x-tile row stride in float4 (68 floats; pad kills stride-64
                         // broadcast bank aliasing)

// ---- float4 helpers -------------------------------------------------------
__device__ __forceinline__ float4 f4fma(float a, const float4 b, float4 c) {
    c.x = fmaf(a, b.x, c.x); c.y = fmaf(a, b.y, c.y);
    c.z = fmaf(a, b.z, c.z); c.w = fmaf(a, b.w, c.w);
    return c;
}

// gcursor[i] = i*CAP (absolute cursors; R4's hipMemsetAsync variant cost +4us).
__global__ void init_kernel(int* __restrict__ gcursor, int nbc) {
    int stride = gridDim.x * blockDim.x;
    for (int i = blockIdx.x * blockDim.x + threadIdx.x; i < nbc; i += stride)
        gcursor[i] = i * CAP;
}

// Fused mid kernel: blocks [0,PB) run the projection, blocks [PB,PB+MSB) run the
// multisplit. The two phases are data-independent; fusing them lets them overlap
// on the device (both individually underutilize it).
// LDS is a union (25.6 KB) -> 6 blocks/CU, 1152 blocks all co-resident.
//
// proj: h_half = fp16(x @ W_src); a_src = (x@W_src)@att_src; a_dst = x@vdst.
//   vdst[k] = sum_h W_dst[k][h]*att_dst[h] recomputed per block (64 thr x 64 FMA,
//   W_dst L2-hot). K-loop unrolled only 4x: full unroll made the compiler hoist
//   LDS loads -> spill to scratch -> ~950 MB phantom HBM traffic (old lesson).
// multisplit: bucket i owns rec[i*CAP,(i+1)*CAP). LDS hist -> one global-atomic
//   reservation per bucket per block -> LDS-cursor placement. Record =
//   (src<<6)|(tgt&63). Same-block writes are contiguous ~20 B runs -> no 16x
//   random write-back amplification (old lesson).
__global__ void __launch_bounds__(256)
mid_kernel(const float* __restrict__ x,
           const float* __restrict__ W_src,
           const float* __restrict__ W_dst,
           const float* __restrict__ att_src,
           const float* __restrict__ att_dst,
           __half* __restrict__ h_half,
           float* __restrict__ a_src,
           float* __restrict__ a_dst, int N,
           const int* __restrict__ src, const int* __restrict__ tgt,
           int* __restrict__ gcursor, int* __restrict__ rec, int E, int nbc) {
    __shared__ __align__(16) char smraw[25600];
    const int t = threadIdx.x;

    if (blockIdx.x < PB) {
        // ---------------- projection ----------------
        float4* Ws4  = (float4*)smraw;        // [HID*16]  (16 KB)
        float4* att4 = Ws4 + HID * 16;        // [16]
        float4* vd4  = att4 + 16;             // [16]
        float4* xs4f = vd4 + 16;              // [32*XSTR] padded x tile (8.5 KB)

        for (int i = t; i < HID * 16; i += 256) Ws4[i] = ((const float4*)W_src)[i];
        if (t < 16) att4[t] = ((const float4*)att_src)[t];
        if (t < HID) {                        // vdst computed locally
            float acc = 0.0f;
#pragma unroll 8
            for (int h = 0; h < HID; ++h)
                acc = fmaf(W_dst[t * HID + h], att_dst[h], acc);
            ((float*)vd4)[t] = acc;
        }

        const int g0 = t >> 4;       // node slot 0..15 (second node = g0+16)
        const int s = t & 15;        // float4 chunk within the 64-wide feature dim
        const float4* x4 = (const float4*)x;
        uint2* h2 = (uint2*)h_half;

        for (int base = blockIdx.x * 32; base < N; base += PB * 32) {
            __syncthreads();  // also covers the Ws4/att4/vd4 fill on iteration 0
#pragma unroll
            for (int u = 0; u < 2; ++u) {
                int f = t + u * 256;                 // flat float4 id 0..511
                int node = base + (f >> 4);
                xs4f[(f >> 4) * XSTR + (f & 15)] =
                    (node < N) ? x4[(long long)node * 16 + (f & 15)]
                               : make_float4(0, 0, 0, 0);
            }
            __syncthreads();

            const float4* xr0 = xs4f + g0 * XSTR;
            const float4* xr1 = xs4f + (g0 + 16) * XSTR;

            float4 acc0 = make_float4(0, 0, 0, 0);
            float4 acc1 = make_float4(0, 0, 0, 0);
#pragma unroll 4
            for (int kk = 0; kk < 16; ++kk) {
                float4 xv0 = xr0[kk];                // broadcast within group
                float4 xv1 = xr1[kk];
                float4 w0 = Ws4[(4 * kk + 0) * 16 + s];
                float4 w1 = Ws4[(4 * kk + 1) * 16 + s];
                float4 w2 = Ws4[(4 * kk + 2) * 16 + s];
                float4 w3 = Ws4[(4 * kk + 3) * 16 + s];
                acc0 = f4fma(xv0.x, w0, acc0);
                acc1 = f4fma(xv1.x, w0, acc1);
                acc0 = f4fma(xv0.y, w1, acc0);
                acc1 = f4fma(xv1.y, w1, acc1);
                acc0 = f4fma(xv0.z, w2, acc0);
                acc1 = f4fma(xv1.z, w2, acc1);
                acc0 = f4fma(xv0.w, w3, acc0);
                acc1 = f4fma(xv1.w, w3, acc1);
            }

            float4 av = att4[s], qv = vd4[s];
            float p0 = acc0.x * av.x + acc0.y * av.y + acc0.z * av.z + acc0.w * av.w;
            float p1 = acc1.x * av.x + acc1.y * av.y + acc1.z * av.z + acc1.w * av.w;
            float4 xq0 = xr0[s];
            float4 xq1 = xr1[s];
            float q0 = xq0.x * qv.x + xq0.y * qv.y + xq0.z * qv.z + xq0.w * qv.w;
            float q1 = xq1.x * qv.x + xq1.y * qv.y + xq1.z * qv.z + xq1.w * qv.w;
#pragma unroll
            for (int off = 1; off < 16; off <<= 1) {
                p0 += __shfl_xor(p0, off, 64);
                p1 += __shfl_xor(p1, off, 64);
                q0 += __shfl_xor(q0, off, 64);
                q1 += __shfl_xor(q1, off, 64);
            }

            int n0 = base + g0, n1 = base + g0 + 16;
            if (n0 < N) {
                __half2 lo = __float22half2_rn(make_float2(acc0.x, acc0.y));
                __half2 hi = __float22half2_rn(make_float2(acc0.z, acc0.w));
                uint2 pk; pk.x = *(unsigned*)&lo; pk.y = *(unsigned*)&hi;
                h2[(long long)n0 * 16 + s] = pk;
                if (s == 0) { a_src[n0] = p0; a_dst[n0] = q0; }
            }
            if (n1 < N) {
                __half2 lo = __float22half2_rn(make_float2(acc1.x, acc1.y));
                __half2 hi = __float22half2_rn(make_float2(acc1.z, acc1.w));
                uint2 pk; pk.x = *(unsigned*)&lo; pk.y = *(unsigned*)&hi;
                h2[(long long)n1 * 16 + s] = pk;
                if (s == 0) { a_src[n1] = p1; a_dst[n1] = q1; }
            }
        }
    } else {
        // ---------------- multisplit ----------------
        int* lh = (int*)smraw;                // [nbc]
        const int bid = blockIdx.x - PB;

        for (int i = t; i < nbc; i += 256) lh[i] = 0;
        __syncthreads();
        int chunk = (E + MSB - 1) / MSB;
        int e0 = bid * chunk;
        int e1 = min(E, e0 + chunk);
        for (int e = e0 + t; e < e1; e += 256)
            atomicAdd(&lh[tgt[e] >> CBITS], 1);
        __syncthreads();
        // reserve: lh[i] becomes this block's base slot for bucket i
        for (int i = t; i < nbc; i += 256)
            if (lh[i]) lh[i] = atomicAdd(&gcursor[i], lh[i]);
        __syncthreads();
        for (int e = e0 + t; e < e1; e += 256) {
            int s = src[e], tg = tgt[e];
            int bi = tg >> CBITS;
            int pos = atomicAdd(&lh[bi], 1);           // LDS atomic (~50cy, not ~500)
            if (pos < (bi + 1) * CAP)                  // overflow guard
                rec[pos] = (s << CBITS) | (tg & (CSZ - 1));
        }
    }
}

// fused fine-sort + WEIGHT PREPASS + gather + output GEMM. ONE block per
// 64-node bucket.
// R5 change: all edge weights w[j] = exp(LeakyReLU(a_src[src_j]+a_dst[tgt_j]))
// are computed in one block-parallel pass over the sorted records BEFORE the
// gather loop. In R0-R4 the random a_src load and the exp sat serially inside
// the per-4-record dependent chain (latency-bound: dur invariant at ~53us
// across occupancy 41-58%, VALUBusy 38%, HBM 19%). In the prepass all ~640
// random a_src loads are independent -> fully pipelined under TLP. The gather
// inner loop keeps only h2-load -> cvt -> fma on its chain, weights come from
// LDS. Weight values / FMA order / dsum order are bit-identical to R4.
// LDS ~24.6 KB -> 6 blocks/CU (1536 co-resident of 1563 -> 1.7% tail).
__global__ void __launch_bounds__(256)
sort_gather_kernel(const int* __restrict__ gcursor, const int* __restrict__ rec,
                   const __half* __restrict__ h_half,
                   const float* __restrict__ a_src, const float* __restrict__ a_dst,
                   const float* __restrict__ bias,
                   const float* __restrict__ W_lin, const float* __restrict__ b_lin,
                   float* __restrict__ out, int N) {
    __shared__ float4 Wl4[HID * 16];   // 16 KB
    __shared__ float4 bs4[16], bl4[16];
    __shared__ int   ssort[CAP];       // 3.25 KB (full record: src<<6 | tl)
    __shared__ float wlds[CAP];        // 3.25 KB (edge weights)
    __shared__ int hist[CSZ];
    __shared__ int loff[CSZ + 1];
    __shared__ int cur[CSZ];
    __shared__ float ladst[CSZ];

    const int t = threadIdx.x;
    for (int i = t; i < HID * 16; i += 256) Wl4[i] = ((const float4*)W_lin)[i];
    if (t < 16) {
        bs4[t] = ((const float4*)bias)[t];
        bl4[t] = ((const float4*)b_lin)[t];
    }

    const int bk = blockIdx.x;
    const int node0 = bk << CBITS;
    const int nn = min(CSZ, N - node0);
    const int beg = bk * CAP;
    int cnt = gcursor[bk] - beg;       // absolute cursor scheme
    if (cnt > CAP) cnt = CAP;

    if (t < CSZ) {
        hist[t] = 0;
        int n = node0 + t;
        ladst[t] = (t < nn) ? a_dst[n] : 0.0f;
    }
    __syncthreads();
    for (int j = t; j < cnt; j += 256)
        atomicAdd(&hist[rec[beg + j] & (CSZ - 1)], 1);
    __syncthreads();
    if (t < CSZ) {                     // wave 0: barrier-free inclusive shfl scan
        int h = hist[t];
        int v = h;
#pragma unroll
        for (int off = 1; off < CSZ; off <<= 1) {
            int u = __shfl_up(v, off, 64);
            if (t >= off) v += u;
        }
        loff[t] = v - h;
        cur[t]  = v - h;
        if (t == CSZ - 1) loff[CSZ] = v;
    }
    __syncthreads();
    for (int j = t; j < cnt; j += 256) {
        int r = rec[beg + j];
        int pos = atomicAdd(&cur[r & (CSZ - 1)], 1);
        ssort[pos] = r;                // pos < cnt <= CAP: no guard needed
    }
    __syncthreads();

    // ---- weight prepass: independent random a_src loads, fully pipelined ----
    for (int j = t; j < cnt; j += 256) {
        int r = ssort[j];
        float v = a_src[r >> CBITS] + ladst[r & (CSZ - 1)];
        v = (v > 0.0f) ? v : 0.2f * v;
        wlds[j] = __expf(v);
    }
    __syncthreads();

    // ---- gather + output GEMM ----
    const int lane = t & 63;
    const int w = t >> 6;
    const int g = lane >> 4;
    const int s = lane & 15;
    const int gbase = g << 4;
    const uint2* h2 = (const uint2*)h_half;
    float4* out4 = (float4*)out;

#pragma unroll 1
    for (int r2 = 0; r2 < 4; ++r2) {
        int nloc = w * 16 + r2 * 4 + g;         // 0..63
        int n = node0 + nloc;
        bool act = (nloc < nn);
        int jb = loff[nloc];
        int je = loff[nloc + 1];

        float4 acc = make_float4(0, 0, 0, 0);
        float dsum = 0.0f;
        int j = jb;
        for (; j + 4 <= je; j += 4) {
            unsigned i0 = ((unsigned)(ssort[j]     >> CBITS) << 4) + s;
            unsigned i1 = ((unsigned)(ssort[j + 1] >> CBITS) << 4) + s;
            unsigned i2 = ((unsigned)(ssort[j + 2] >> CBITS) << 4) + s;
            unsigned i3 = ((unsigned)(ssort[j + 3] >> CBITS) << 4) + s;
            uint2 r0 = h2[i0];
            uint2 r1 = h2[i1];
            uint2 r2v = h2[i2];
            uint2 r3 = h2[i3];
            float w0 = wlds[j], w1 = wlds[j + 1];
            float w2 = wlds[j + 2], w3 = wlds[j + 3];
            dsum += (w0 + w1) + (w2 + w3);
            float2 f0a = __half22float2(*(const __half2*)&r0.x);
            float2 f0b = __half22float2(*(const __half2*)&r0.y);
            float2 f1a = __half22float2(*(const __half2*)&r1.x);
            float2 f1b = __half22float2(*(const __half2*)&r1.y);
            float2 f2a = __half22float2(*(const __half2*)&r2v.x);
            float2 f2b = __half22float2(*(const __half2*)&r2v.y);
            float2 f3a = __half22float2(*(const __half2*)&r3.x);
            float2 f3b = __half22float2(*(const __half2*)&r3.y);
            acc.x = fmaf(w0, f0a.x, fmaf(w1, f1a.x, fmaf(w2, f2a.x, fmaf(w3, f3a.x, acc.x))));
            acc.y = fmaf(w0, f0a.y, fmaf(w1, f1a.y, fmaf(w2, f2a.y, fmaf(w3, f3a.y, acc.y))));
            acc.z = fmaf(w0, f0b.x, fmaf(w1, f1b.x, fmaf(w2, f2b.x, fmaf(w3, f3b.x, acc.z))));
            acc.w = fmaf(w0, f0b.y, fmaf(w1, f1b.y, fmaf(w2, f2b.y, fmaf(w3, f3b.y, acc.w))));
        }
        for (; j < je; ++j) {
            unsigned i0 = ((unsigned)(ssort[j] >> CBITS) << 4) + s;
            uint2 r0 = h2[i0];
            float w0 = wlds[j];
            dsum += w0;
            float2 f0a = __half22float2(*(const __half2*)&r0.x);
            float2 f0b = __half22float2(*(const __half2*)&r0.y);
            acc.x = fmaf(w0, f0a.x, acc.x);
            acc.y = fmaf(w0, f0a.y, acc.y);
            acc.z = fmaf(w0, f0b.x, acc.z);
            acc.w = fmaf(w0, f0b.y, acc.w);
        }

        float inv = 1.0f / (dsum + 1e-16f);
        float4 bsv = bs4[s];
        float4 r;
        r.x = fmaf(acc.x, inv, bsv.x);
        r.y = fmaf(acc.y, inv, bsv.y);
        r.z = fmaf(acc.z, inv, bsv.z);
        r.w = fmaf(acc.w, inv, bsv.w);

        float4 o = bl4[s];
#pragma unroll 4
        for (int ks = 0; ks < 16; ++ks) {
            float rx = __shfl(r.x, gbase + ks, 64);
            float ry = __shfl(r.y, gbase + ks, 64);
            float rz = __shfl(r.z, gbase + ks, 64);
            float rw = __shfl(r.w, gbase + ks, 64);
            o = f4fma(rx, Wl4[(4 * ks + 0) * 16 + s], o);
            o = f4fma(ry, Wl4[(4 * ks + 1) * 16 + s], o);
            o = f4fma(rz, Wl4[(4 * ks + 2) * 16 + s], o);
            o = f4fma(rw, Wl4[(4 * ks + 3) * 16 + s], o);
        }

        if (act) {
            float4 res;
            res.x = o.x > 0.0f ? o.x : 0.0f;
            res.y = o.y > 0.0f ? o.y : 0.0f;
            res.z = o.z > 0.0f ? o.z : 0.0f;
            res.w = o.w > 0.0f ? o.w : 0.0f;
            out4[(long long)n * 16 + s] = res;
        }
    }
}

extern "C" void kernel_launch(void* const* d_in, const int* in_sizes, int n_in,
                              void* d_out, int out_size, void* d_ws, size_t ws_size,
                              hipStream_t stream) {
    const float* x       = (const float*)d_in[0];
    const int*   edge    = (const int*)d_in[1];
    const float* W_src   = (const float*)d_in[2];
    const float* W_dst   = (const float*)d_in[3];
    const float* att_src = (const float*)d_in[4];
    const float* att_dst = (const float*)d_in[5];
    const float* bias    = (const float*)d_in[6];
    const float* W_lin   = (const float*)d_in[7];
    const float* b_lin   = (const float*)d_in[8];
    float* out = (float*)d_out;

    const int N = in_sizes[0] / HID;  // 100000
    const int E = in_sizes[1] / 2;    // 1000000
    const int* src = edge;
    const int* tgt = edge + E;
    const int nbc = (N + CSZ - 1) / CSZ;   // 1563 buckets

    // workspace layout
    __half* h_half  = (__half*)d_ws;                      // N*HID halves
    float*  a_src   = (float*)(h_half + (size_t)N * HID); // N
    float*  a_dst   = a_src + N;                          // N
    int*    gcursor = (int*)(a_dst + N);                  // MAXB
    int*    rec     = gcursor + MAXB;                     // nbc*CAP (~5.2 MB)

    init_kernel<<<8, 256, 0, stream>>>(gcursor, nbc);
    mid_kernel<<<PB + MSB, 256, 0, stream>>>(x, W_src, W_dst, att_src, att_dst,
                                             h_half, a_src, a_dst, N,
                                             src, tgt, gcursor, rec, E, nbc);
    sort_gather_kernel<<<nbc, 256, 0, stream>>>(gcursor, rec, h_half, a_src, a_dst,
                                                bias, W_lin, b_lin, out, N);
}

// Round 6
// 165.301 us; speedup vs baseline: 1.0470x; 1.0470x over previous
//
#include <hip/hip_runtime.h>
#include <hip/hip_fp16.h>
#include <math.h>

#define HID 64
#define CBITS 6
#define CSZ 64           // nodes per bucket
#define MAXB 2048        // max buckets supported (N <= 131072)
#define CAP 832          // record slots per bucket (mean 640, sigma ~25 -> +7.6 sigma)
#define PB 896           // proj blocks in the fused mid kernel
#define MSB 256          // multisplit blocks in the fused mid kernel
#define XSTR 17          // x-tile row stride in float4 (68 floats; pad kills stride-64
                         // broadcast bank aliasing)

// ---- float4 helpers -------------------------------------------------------
__device__ __forceinline__ float4 f4fma(float a, const float4 b, float4 c) {
    c.x = fmaf(a, b.x, c.x); c.y = fmaf(a, b.y, c.y);
    c.z = fmaf(a, b.z, c.z); c.w = fmaf(a, b.w, c.w);
    return c;
}

// gcursor[i] = i*CAP (absolute cursors; R4's hipMemsetAsync variant cost +4us).
__global__ void init_kernel(int* __restrict__ gcursor, int nbc) {
    int stride = gridDim.x * blockDim.x;
    for (int i = blockIdx.x * blockDim.x + threadIdx.x; i < nbc; i += stride)
        gcursor[i] = i * CAP;
}

// Fused mid kernel: blocks [0,PB) run the projection, blocks [PB,PB+MSB) run the
// multisplit. The two phases are data-independent; fusing them lets them overlap
// on the device (both individually underutilize it).
// LDS is a union (25.6 KB) -> 6 blocks/CU, 1152 blocks all co-resident.
//
// proj: h_half = fp16(x @ W_src); a_src = (x@W_src)@att_src; a_dst = x@vdst.
//   vdst[k] = sum_h W_dst[k][h]*att_dst[h] recomputed per block (64 thr x 64 FMA,
//   W_dst L2-hot). K-loop unrolled only 4x: full unroll made the compiler hoist
//   LDS loads -> spill to scratch -> ~950 MB phantom HBM traffic (old lesson).
// multisplit: bucket i owns rec[i*CAP,(i+1)*CAP). LDS hist -> one global-atomic
//   reservation per bucket per block -> LDS-cursor placement. Record =
//   (src<<6)|(tgt&63). Same-block writes are contiguous ~20 B runs -> no 16x
//   random write-back amplification (old lesson).
__global__ void __launch_bounds__(256)
mid_kernel(const float* __restrict__ x,
           const float* __restrict__ W_src,
           const float* __restrict__ W_dst,
           const float* __restrict__ att_src,
           const float* __restrict__ att_dst,
           __half* __restrict__ h_half,
           float* __restrict__ a_src,
           float* __restrict__ a_dst, int N,
           const int* __restrict__ src, const int* __restrict__ tgt,
           int* __restrict__ gcursor, int* __restrict__ rec, int E, int nbc) {
    __shared__ __align__(16) char smraw[25600];
    const int t = threadIdx.x;

    if (blockIdx.x < PB) {
        // ---------------- projection ----------------
        float4* Ws4  = (float4*)smraw;        // [HID*16]  (16 KB)
        float4* att4 = Ws4 + HID * 16;        // [16]
        float4* vd4  = att4 + 16;             // [16]
        float4* xs4f = vd4 + 16;              // [32*XSTR] padded x tile (8.5 KB)

        for (int i = t; i < HID * 16; i += 256) Ws4[i] = ((const float4*)W_src)[i];
        if (t < 16) att4[t] = ((const float4*)att_src)[t];
        if (t < HID) {                        // vdst computed locally
            float acc = 0.0f;
#pragma unroll 8
            for (int h = 0; h < HID; ++h)
                acc = fmaf(W_dst[t * HID + h], att_dst[h], acc);
            ((float*)vd4)[t] = acc;
        }

        const int g0 = t >> 4;       // node slot 0..15 (second node = g0+16)
        const int s = t & 15;        // float4 chunk within the 64-wide feature dim
        const float4* x4 = (const float4*)x;
        uint2* h2 = (uint2*)h_half;

        for (int base = blockIdx.x * 32; base < N; base += PB * 32) {
            __syncthreads();  // also covers the Ws4/att4/vd4 fill on iteration 0
#pragma unroll
            for (int u = 0; u < 2; ++u) {
                int f = t + u * 256;                 // flat float4 id 0..511
                int node = base + (f >> 4);
                xs4f[(f >> 4) * XSTR + (f & 15)] =
                    (node < N) ? x4[(long long)node * 16 + (f & 15)]
                               : make_float4(0, 0, 0, 0);
            }
            __syncthreads();

            const float4* xr0 = xs4f + g0 * XSTR;
            const float4* xr1 = xs4f + (g0 + 16) * XSTR;

            float4 acc0 = make_float4(0, 0, 0, 0);
            float4 acc1 = make_float4(0, 0, 0, 0);
#pragma unroll 4
            for (int kk = 0; kk < 16; ++kk) {
                float4 xv0 = xr0[kk];                // broadcast within group
                float4 xv1 = xr1[kk];
                float4 w0 = Ws4[(4 * kk + 0) * 16 + s];
                float4 w1 = Ws4[(4 * kk + 1) * 16 + s];
                float4 w2 = Ws4[(4 * kk + 2) * 16 + s];
                float4 w3 = Ws4[(4 * kk + 3) * 16 + s];
                acc0 = f4fma(xv0.x, w0, acc0);
                acc1 = f4fma(xv1.x, w0, acc1);
                acc0 = f4fma(xv0.y, w1, acc0);
                acc1 = f4fma(xv1.y, w1, acc1);
                acc0 = f4fma(xv0.z, w2, acc0);
                acc1 = f4fma(xv1.z, w2, acc1);
                acc0 = f4fma(xv0.w, w3, acc0);
                acc1 = f4fma(xv1.w, w3, acc1);
            }

            float4 av = att4[s], qv = vd4[s];
            float p0 = acc0.x * av.x + acc0.y * av.y + acc0.z * av.z + acc0.w * av.w;
            float p1 = acc1.x * av.x + acc1.y * av.y + acc1.z * av.z + acc1.w * av.w;
            float4 xq0 = xr0[s];
            float4 xq1 = xr1[s];
            float q0 = xq0.x * qv.x + xq0.y * qv.y + xq0.z * qv.z + xq0.w * qv.w;
            float q1 = xq1.x * qv.x + xq1.y * qv.y + xq1.z * qv.z + xq1.w * qv.w;
#pragma unroll
            for (int off = 1; off < 16; off <<= 1) {
                p0 += __shfl_xor(p0, off, 64);
                p1 += __shfl_xor(p1, off, 64);
                q0 += __shfl_xor(q0, off, 64);
                q1 += __shfl_xor(q1, off, 64);
            }

            int n0 = base + g0, n1 = base + g0 + 16;
            if (n0 < N) {
                __half2 lo = __float22half2_rn(make_float2(acc0.x, acc0.y));
                __half2 hi = __float22half2_rn(make_float2(acc0.z, acc0.w));
                uint2 pk; pk.x = *(unsigned*)&lo; pk.y = *(unsigned*)&hi;
                h2[(long long)n0 * 16 + s] = pk;
                if (s == 0) { a_src[n0] = p0; a_dst[n0] = q0; }
            }
            if (n1 < N) {
                __half2 lo = __float22half2_rn(make_float2(acc1.x, acc1.y));
                __half2 hi = __float22half2_rn(make_float2(acc1.z, acc1.w));
                uint2 pk; pk.x = *(unsigned*)&lo; pk.y = *(unsigned*)&hi;
                h2[(long long)n1 * 16 + s] = pk;
                if (s == 0) { a_src[n1] = p1; a_dst[n1] = q1; }
            }
        }
    } else {
        // ---------------- multisplit ----------------
        int* lh = (int*)smraw;                // [nbc]
        const int bid = blockIdx.x - PB;

        for (int i = t; i < nbc; i += 256) lh[i] = 0;
        __syncthreads();
        int chunk = (E + MSB - 1) / MSB;
        int e0 = bid * chunk;
        int e1 = min(E, e0 + chunk);
        for (int e = e0 + t; e < e1; e += 256)
            atomicAdd(&lh[tgt[e] >> CBITS], 1);
        __syncthreads();
        // reserve: lh[i] becomes this block's base slot for bucket i
        for (int i = t; i < nbc; i += 256)
            if (lh[i]) lh[i] = atomicAdd(&gcursor[i], lh[i]);
        __syncthreads();
        for (int e = e0 + t; e < e1; e += 256) {
            int s = src[e], tg = tgt[e];
            int bi = tg >> CBITS;
            int pos = atomicAdd(&lh[bi], 1);           // LDS atomic (~50cy, not ~500)
            if (pos < (bi + 1) * CAP)                  // overflow guard
                rec[pos] = (s << CBITS) | (tg & (CSZ - 1));
        }
    }
}

// fused fine-sort + gather + output GEMM. ONE block per 64-node bucket.
// R6 changes (R5 prepass reverted -- it regressed 53->59us):
//  * SOFTWARE PIPELINE: the edge loop issues iteration i+1's 4 h2 loads + 4
//    a_src loads before computing iteration i. The R0-R5 loop was latency-bound
//    on ds_read->addr->global(~700cy L3)->fma with 4 loads in flight and zero
//    cross-iteration overlap (dur invariant ~53us across occupancy 41-58%).
//  * LDS 21.5K -> 20.2 KB (bias/b_lin in registers, cursor folded into hist,
//    single register-staged rec pass) + __launch_bounds__(256,8): 8 blocks/CU
//    and the 64-VGPR cap that makes 8 waves/SIMD reachable.
// Per-4-edge arithmetic (grouping, FMA order, dsum order) identical to R4.
__global__ void __launch_bounds__(256, 8)
sort_gather_kernel(const int* __restrict__ gcursor, const int* __restrict__ rec,
                   const __half* __restrict__ h_half,
                   const float* __restrict__ a_src, const float* __restrict__ a_dst,
                   const float* __restrict__ bias,
                   const float* __restrict__ W_lin, const float* __restrict__ b_lin,
                   float* __restrict__ out, int N) {
    __shared__ float4 Wl4[HID * 16];   // 16 KB
    __shared__ int   ssort[CAP];       // 3.25 KB (full record: src<<6 | tl)
    __shared__ int   loff[CSZ + 1];    // 260 B
    __shared__ int   hist[CSZ];        // 256 B (reused as placement cursor)

    const int t = threadIdx.x;
    for (int i = t; i < HID * 16; i += 256) Wl4[i] = ((const float4*)W_lin)[i];

    const int bk = blockIdx.x;
    const int node0 = bk << CBITS;
    const int nn = min(CSZ, N - node0);
    const int beg = bk * CAP;
    int cnt = gcursor[bk] - beg;       // absolute cursor scheme
    if (cnt > CAP) cnt = CAP;

    if (t < CSZ) hist[t] = 0;
    __syncthreads();

    // single global pass over rec: stage into 4 named registers (static idx)
    int q0 = (t       < cnt) ? rec[beg + t      ] : -1;
    int q1 = (t + 256 < cnt) ? rec[beg + t + 256] : -1;
    int q2 = (t + 512 < cnt) ? rec[beg + t + 512] : -1;
    int q3 = (t + 768 < cnt) ? rec[beg + t + 768] : -1;
    if (q0 >= 0) atomicAdd(&hist[q0 & (CSZ - 1)], 1);
    if (q1 >= 0) atomicAdd(&hist[q1 & (CSZ - 1)], 1);
    if (q2 >= 0) atomicAdd(&hist[q2 & (CSZ - 1)], 1);
    if (q3 >= 0) atomicAdd(&hist[q3 & (CSZ - 1)], 1);
    __syncthreads();
    if (t < CSZ) {                     // wave 0: barrier-free inclusive shfl scan
        int h = hist[t];
        int v = h;
#pragma unroll
        for (int off = 1; off < CSZ; off <<= 1) {
            int u = __shfl_up(v, off, 64);
            if (t >= off) v += u;
        }
        loff[t] = v - h;
        hist[t] = v - h;               // hist becomes the placement cursor
        if (t == CSZ - 1) loff[CSZ] = v;
    }
    __syncthreads();
    if (q0 >= 0) ssort[atomicAdd(&hist[q0 & (CSZ - 1)], 1)] = q0;
    if (q1 >= 0) ssort[atomicAdd(&hist[q1 & (CSZ - 1)], 1)] = q1;
    if (q2 >= 0) ssort[atomicAdd(&hist[q2 & (CSZ - 1)], 1)] = q2;
    if (q3 >= 0) ssort[atomicAdd(&hist[q3 & (CSZ - 1)], 1)] = q3;
    __syncthreads();

    // ---- gather + output GEMM ----
    const int lane = t & 63;
    const int w = t >> 6;
    const int g = lane >> 4;
    const int s = lane & 15;
    const int gbase = g << 4;
    const uint2* h2 = (const uint2*)h_half;
    float4* out4 = (float4*)out;
    const float4 bsv = ((const float4*)bias)[s];
    const float4 blv = ((const float4*)b_lin)[s];

#pragma unroll 1
    for (int r2 = 0; r2 < 4; ++r2) {
        int nloc = w * 16 + r2 * 4 + g;         // 0..63
        int n = node0 + nloc;
        bool act = (nloc < nn);
        float adn = act ? a_dst[n] : 0.0f;
        int jb = loff[nloc];
        int je = loff[nloc + 1];

        float4 acc = make_float4(0, 0, 0, 0);
        float dsum = 0.0f;
        int j = jb;
        uint2 pr0 = make_uint2(0, 0), pr1 = pr0, pr2 = pr0, pr3 = pr0;
        float pa0 = 0.0f, pa1 = 0.0f, pa2 = 0.0f, pa3 = 0.0f;
        if (j + 4 <= je) {              // prologue: issue stage for j..j+3
            int c0 = ssort[j] >> CBITS,     c1 = ssort[j + 1] >> CBITS;
            int c2 = ssort[j + 2] >> CBITS, c3 = ssort[j + 3] >> CBITS;
            pr0 = h2[((unsigned)c0 << 4) + s];
            pr1 = h2[((unsigned)c1 << 4) + s];
            pr2 = h2[((unsigned)c2 << 4) + s];
            pr3 = h2[((unsigned)c3 << 4) + s];
            pa0 = a_src[c0]; pa1 = a_src[c1]; pa2 = a_src[c2]; pa3 = a_src[c3];
        }
#pragma unroll 1
        for (; j + 8 <= je; j += 4) {
            // issue next stage (j+4..j+7) -- flies while we compute current
            int c0 = ssort[j + 4] >> CBITS, c1 = ssort[j + 5] >> CBITS;
            int c2 = ssort[j + 6] >> CBITS, c3 = ssort[j + 7] >> CBITS;
            uint2 nr0 = h2[((unsigned)c0 << 4) + s];
            uint2 nr1 = h2[((unsigned)c1 << 4) + s];
            uint2 nr2 = h2[((unsigned)c2 << 4) + s];
            uint2 nr3 = h2[((unsigned)c3 << 4) + s];
            float na0 = a_src[c0], na1 = a_src[c1];
            float na2 = a_src[c2], na3 = a_src[c3];
            // compute current stage
            float v0 = pa0 + adn, v1 = pa1 + adn, v2 = pa2 + adn, v3 = pa3 + adn;
            v0 = (v0 > 0.0f) ? v0 : 0.2f * v0;
            v1 = (v1 > 0.0f) ? v1 : 0.2f * v1;
            v2 = (v2 > 0.0f) ? v2 : 0.2f * v2;
            v3 = (v3 > 0.0f) ? v3 : 0.2f * v3;
            float w0 = __expf(v0), w1 = __expf(v1);
            float w2 = __expf(v2), w3 = __expf(v3);
            dsum += (w0 + w1) + (w2 + w3);
            float2 f0a = __half22float2(*(const __half2*)&pr0.x);
            float2 f0b = __half22float2(*(const __half2*)&pr0.y);
            float2 f1a = __half22float2(*(const __half2*)&pr1.x);
            float2 f1b = __half22float2(*(const __half2*)&pr1.y);
            float2 f2a = __half22float2(*(const __half2*)&pr2.x);
            float2 f2b = __half22float2(*(const __half2*)&pr2.y);
            float2 f3a = __half22float2(*(const __half2*)&pr3.x);
            float2 f3b = __half22float2(*(const __half2*)&pr3.y);
            acc.x = fmaf(w0, f0a.x, fmaf(w1, f1a.x, fmaf(w2, f2a.x, fmaf(w3, f3a.x, acc.x))));
            acc.y = fmaf(w0, f0a.y, fmaf(w1, f1a.y, fmaf(w2, f2a.y, fmaf(w3, f3a.y, acc.y))));
            acc.z = fmaf(w0, f0b.x, fmaf(w1, f1b.x, fmaf(w2, f2b.x, fmaf(w3, f3b.x, acc.z))));
            acc.w = fmaf(w0, f0b.y, fmaf(w1, f1b.y, fmaf(w2, f2b.y, fmaf(w3, f3b.y, acc.w))));
            pr0 = nr0; pr1 = nr1; pr2 = nr2; pr3 = nr3;
            pa0 = na0; pa1 = na1; pa2 = na2; pa3 = na3;
        }
        if (j + 4 <= je) {              // drain the pipelined stage
            float v0 = pa0 + adn, v1 = pa1 + adn, v2 = pa2 + adn, v3 = pa3 + adn;
            v0 = (v0 > 0.0f) ? v0 : 0.2f * v0;
            v1 = (v1 > 0.0f) ? v1 : 0.2f * v1;
            v2 = (v2 > 0.0f) ? v2 : 0.2f * v2;
            v3 = (v3 > 0.0f) ? v3 : 0.2f * v3;
            float w0 = __expf(v0), w1 = __expf(v1);
            float w2 = __expf(v2), w3 = __expf(v3);
            dsum += (w0 + w1) + (w2 + w3);
            float2 f0a = __half22float2(*(const __half2*)&pr0.x);
            float2 f0b = __half22float2(*(const __half2*)&pr0.y);
            float2 f1a = __half22float2(*(const __half2*)&pr1.x);
            float2 f1b = __half22float2(*(const __half2*)&pr1.y);
            float2 f2a = __half22float2(*(const __half2*)&pr2.x);
            float2 f2b = __half22float2(*(const __half2*)&pr2.y);
            float2 f3a = __half22float2(*(const __half2*)&pr3.x);
            float2 f3b = __half22float2(*(const __half2*)&pr3.y);
            acc.x = fmaf(w0, f0a.x, fmaf(w1, f1a.x, fmaf(w2, f2a.x, fmaf(w3, f3a.x, acc.x))));
            acc.y = fmaf(w0, f0a.y, fmaf(w1, f1a.y, fmaf(w2, f2a.y, fmaf(w3, f3a.y, acc.y))));
            acc.z = fmaf(w0, f0b.x, fmaf(w1, f1b.x, fmaf(w2, f2b.x, fmaf(w3, f3b.x, acc.z))));
            acc.w = fmaf(w0, f0b.y, fmaf(w1, f1b.y, fmaf(w2, f2b.y, fmaf(w3, f3b.y, acc.w))));
            j += 4;
        }
        for (; j < je; ++j) {           // scalar tail
            int c0 = ssort[j] >> CBITS;
            uint2 r0 = h2[((unsigned)c0 << 4) + s];
            float v0 = a_src[c0] + adn;
            v0 = (v0 > 0.0f) ? v0 : 0.2f * v0;
            float w0 = __expf(v0);
            dsum += w0;
            float2 f0a = __half22float2(*(const __half2*)&r0.x);
            float2 f0b = __half22float2(*(const __half2*)&r0.y);
            acc.x = fmaf(w0, f0a.x, acc.x);
            acc.y = fmaf(w0, f0a.y, acc.y);
            acc.z = fmaf(w0, f0b.x, acc.z);
            acc.w = fmaf(w0, f0b.y, acc.w);
        }

        float inv = 1.0f / (dsum + 1e-16f);
        float4 r;
        r.x = fmaf(acc.x, inv, bsv.x);
        r.y = fmaf(acc.y, inv, bsv.y);
        r.z = fmaf(acc.z, inv, bsv.z);
        r.w = fmaf(acc.w, inv, bsv.w);

        float4 o = blv;
#pragma unroll 4
        for (int ks = 0; ks < 16; ++ks) {
            float rx = __shfl(r.x, gbase + ks, 64);
            float ry = __shfl(r.y, gbase + ks, 64);
            float rz = __shfl(r.z, gbase + ks, 64);
            float rw = __shfl(r.w, gbase + ks, 64);
            o = f4fma(rx, Wl4[(4 * ks + 0) * 16 + s], o);
            o = f4fma(ry, Wl4[(4 * ks + 1) * 16 + s], o);
            o = f4fma(rz, Wl4[(4 * ks + 2) * 16 + s], o);
            o = f4fma(rw, Wl4[(4 * ks + 3) * 16 + s], o);
        }

        if (act) {
            float4 res;
            res.x = o.x > 0.0f ? o.x : 0.0f;
            res.y = o.y > 0.0f ? o.y : 0.0f;
            res.z = o.z > 0.0f ? o.z : 0.0f;
            res.w = o.w > 0.0f ? o.w : 0.0f;
            out4[(long long)n * 16 + s] = res;
        }
    }
}

extern "C" void kernel_launch(void* const* d_in, const int* in_sizes, int n_in,
                              void* d_out, int out_size, void* d_ws, size_t ws_size,
                              hipStream_t stream) {
    const float* x       = (const float*)d_in[0];
    const int*   edge    = (const int*)d_in[1];
    const float* W_src   = (const float*)d_in[2];
    const float* W_dst   = (const float*)d_in[3];
    const float* att_src = (const float*)d_in[4];
    const float* att_dst = (const float*)d_in[5];
    const float* bias    = (const float*)d_in[6];
    const float* W_lin   = (const float*)d_in[7];
    const float* b_lin   = (const float*)d_in[8];
    float* out = (float*)d_out;

    const int N = in_sizes[0] / HID;  // 100000
    const int E = in_sizes[1] / 2;    // 1000000
    const int* src = edge;
    const int* tgt = edge + E;
    const int nbc = (N + CSZ - 1) / CSZ;   // 1563 buckets

    // workspace layout
    __half* h_half  = (__half*)d_ws;                      // N*HID halves
    float*  a_src   = (float*)(h_half + (size_t)N * HID); // N
    float*  a_dst   = a_src + N;                          // N
    int*    gcursor = (int*)(a_dst + N);                  // MAXB
    int*    rec     = gcursor + MAXB;                     // nbc*CAP (~5.2 MB)

    init_kernel<<<8, 256, 0, stream>>>(gcursor, nbc);
    mid_kernel<<<PB + MSB, 256, 0, stream>>>(x, W_src, W_dst, att_src, att_dst,
                                             h_half, a_src, a_dst, N,
                                             src, tgt, gcursor, rec, E, nbc);
    sort_gather_kernel<<<nbc, 256, 0, stream>>>(gcursor, rec, h_half, a_src, a_dst,
                                                bias, W_lin, b_lin, out, N);
}